// Round 6
// baseline (691.842 us; speedup 1.0000x reference)
//
#include <hip/hip_runtime.h>
#include <hip/hip_bf16.h>
#include <math.h>

// B=4, S=2048, C=1024, H=16, HS=64
// Inputs (fp32, dict order): x[4,2048,1024], Wq/Wk/Wv[16,1024,64],
//                            Wp[1024,1024], bp[1024]
// Output: FP32 [4,2048,1024]  (reference output dtype is float32; the
// "bf16" in the test's error label is hardcoded in its f-string).
// Per-batch pipeline (ws = 16 MB): QKV GEMM -> flash attention -> out-proj.
// MFMA math cross-validated: r2-r4 (MFMA) == r5 (pure VALU) bit-identical.

typedef __bf16 bf16_t;
typedef __bf16 bf16x8 __attribute__((ext_vector_type(8)));
typedef float f32x4 __attribute__((ext_vector_type(4)));

#define S_LEN 2048
#define C_DIM 1024
#define NHEAD 16
#define HS_DIM 64

// Convert 8 contiguous fp32 -> 8 bf16, store to 16B-aligned LDS address.
__device__ __forceinline__ void cvt8(bf16_t* dst, const float* __restrict__ src) {
  const float4 a = *(const float4*)src;
  const float4 b = *(const float4*)(src + 4);
  bf16x8 v;
  v[0] = (bf16_t)a.x; v[1] = (bf16_t)a.y; v[2] = (bf16_t)a.z; v[3] = (bf16_t)a.w;
  v[4] = (bf16_t)b.x; v[5] = (bf16_t)b.y; v[6] = (bf16_t)b.z; v[7] = (bf16_t)b.w;
  *(bf16x8*)dst = v;
}

// ---------------------------------------------------------------------------
// QKV projection for ONE batch: [2048,1024]x{Wq,Wk,Wv}. 64x64x64 tiles,
// 256 thr = 4 waves; wave w owns rows [w*16,w*16+16) x 64 cols.
// A tile: x fp32 -> bf16 LDS. B tile: W[h][c][d] fp32 -> Bs[d][c] (transpose).
// Epilogue scatters Q[s,h*64+d], K[s,h*64+d], VT[h,d,s].
// ---------------------------------------------------------------------------
__global__ __launch_bounds__(256) void gemm_qkv_kernel(
    const float* __restrict__ x,      // [2048,1024] (one batch)
    const float* __restrict__ Wq, const float* __restrict__ Wk,
    const float* __restrict__ Wv,
    bf16_t* __restrict__ Q,           // [2048,1024]
    bf16_t* __restrict__ K,           // [2048,1024]
    bf16_t* __restrict__ VT) {        // [16,64,2048]
  __shared__ __align__(16) bf16_t As[64][72];
  __shared__ __align__(16) bf16_t Bs[64][72];
  const int m0 = blockIdx.x * 64;
  const int n0 = blockIdx.y * 64;     // n = wsel*1024 + h*64 + d
  const int wsel = n0 >> 10;
  const int h = (n0 >> 6) & 15;
  const float* W = (wsel == 0 ? Wq : (wsel == 1 ? Wk : Wv)) + (size_t)h * (C_DIM * HS_DIM);

  const int tid = threadIdx.x;
  const int wave = tid >> 6, lane = tid & 63, quad = lane >> 4, lid = lane & 15;
  const int sr = tid >> 3;            // 0..31
  const int sc = (tid & 7) << 3;      // 0..56
  const int bc = tid >> 2;            // 0..63  (c index for B transpose)
  const int bd = (tid & 3) << 4;      // 0,16,32,48 (d start)

  f32x4 acc[4] = {};

  for (int k0 = 0; k0 < C_DIM; k0 += 64) {
    // A: x rows m0+sr(+32), cols k0+sc..+8, fp32->bf16
    cvt8(&As[sr][sc],      x + (size_t)(m0 + sr) * C_DIM + k0 + sc);
    cvt8(&As[sr + 32][sc], x + (size_t)(m0 + sr + 32) * C_DIM + k0 + sc);
    // B (transpose): Bs[d][c] = W[k0+bc][d], d = bd..bd+15
    {
      const float* Wrow = W + (size_t)(k0 + bc) * HS_DIM + bd;
      #pragma unroll
      for (int j = 0; j < 16; j += 4) {
        const float4 w4 = *(const float4*)(Wrow + j);
        Bs[bd + j + 0][bc] = (bf16_t)w4.x;
        Bs[bd + j + 1][bc] = (bf16_t)w4.y;
        Bs[bd + j + 2][bc] = (bf16_t)w4.z;
        Bs[bd + j + 3][bc] = (bf16_t)w4.w;
      }
    }
    __syncthreads();
    #pragma unroll
    for (int c = 0; c < 2; ++c) {
      bf16x8 afrag = *(const bf16x8*)&As[wave * 16 + lid][c * 32 + quad * 8];
      #pragma unroll
      for (int nt = 0; nt < 4; ++nt) {
        bf16x8 bfrag = *(const bf16x8*)&Bs[nt * 16 + lid][c * 32 + quad * 8];
        acc[nt] = __builtin_amdgcn_mfma_f32_16x16x32_bf16(afrag, bfrag, acc[nt], 0, 0, 0);
      }
    }
    __syncthreads();
  }

  #pragma unroll
  for (int nt = 0; nt < 4; ++nt) {
    #pragma unroll
    for (int r = 0; r < 4; ++r) {
      const int s = m0 + wave * 16 + quad * 4 + r;   // C/D row
      const int d = nt * 16 + lid;                   // C/D col (local d)
      const bf16_t bv = (bf16_t)acc[nt][r];
      if (wsel == 0) {
        Q[(size_t)s * C_DIM + h * HS_DIM + d] = bv;
      } else if (wsel == 1) {
        K[(size_t)s * C_DIM + h * HS_DIM + d] = bv;
      } else {
        VT[((size_t)h * HS_DIM + d) * S_LEN + s] = bv;
      }
    }
  }
}

// ---------------------------------------------------------------------------
// Flash attention (causal) for ONE batch. Block = 4 waves, one (h, 64-row
// Q tile). Wave owns a 16-row strip; online softmax; P via wave-private LDS
// (C-layout -> A-layout, m120 pattern).
// ---------------------------------------------------------------------------
__global__ __launch_bounds__(256) void flash_attn_kernel(
    const bf16_t* __restrict__ Q,   // [2048,1024]
    const bf16_t* __restrict__ Kb,  // [2048,1024]
    const bf16_t* __restrict__ VT,  // [16,64,2048]
    bf16_t* __restrict__ O) {       // [2048,1024]
  __shared__ __align__(16) bf16_t Ks[64][72];
  __shared__ __align__(16) bf16_t Vs[64][72];
  __shared__ __align__(16) bf16_t Ps[4][16][72];
  const int s0 = blockIdx.x * 64;
  const int h = blockIdx.y;
  const int tid = threadIdx.x;
  const int wave = tid >> 6, lane = tid & 63, quad = lane >> 4, lid = lane & 15;

  // Q fragments (A-layout): row = s0 + wave*16 + lid, k = c*32 + quad*8 + j
  const size_t qbase = (size_t)(s0 + wave * 16 + lid) * C_DIM + h * HS_DIM;
  bf16x8 qfrag[2];
  qfrag[0] = *(const bf16x8*)(Q + qbase + quad * 8);
  qfrag[1] = *(const bf16x8*)(Q + qbase + 32 + quad * 8);

  f32x4 oacc[4] = {};
  float m_i[4], l_i[4];
  #pragma unroll
  for (int r = 0; r < 4; ++r) { m_i[r] = -INFINITY; l_i[r] = 0.f; }

  const int sr = tid >> 3, sc = (tid & 7) << 3;
  const float scale = 0.125f;  // 1/sqrt(64)

  for (int t0 = 0; t0 <= s0; t0 += 64) {
    __syncthreads();
    *(uint4*)&Ks[sr][sc]      = *(const uint4*)(Kb + (size_t)(t0 + sr) * C_DIM + h * HS_DIM + sc);
    *(uint4*)&Ks[sr + 32][sc] = *(const uint4*)(Kb + (size_t)(t0 + sr + 32) * C_DIM + h * HS_DIM + sc);
    *(uint4*)&Vs[sr][sc]      = *(const uint4*)(VT + ((size_t)h * HS_DIM + sr) * S_LEN + t0 + sc);
    *(uint4*)&Vs[sr + 32][sc] = *(const uint4*)(VT + ((size_t)h * HS_DIM + sr + 32) * S_LEN + t0 + sc);
    __syncthreads();

    // S = Q K^T (wave strip: 16 rows x 64 cols)
    f32x4 sacc[4] = {};
    #pragma unroll
    for (int c = 0; c < 2; ++c) {
      #pragma unroll
      for (int nt = 0; nt < 4; ++nt) {
        bf16x8 bfrag = *(const bf16x8*)&Ks[nt * 16 + lid][c * 32 + quad * 8];
        sacc[nt] = __builtin_amdgcn_mfma_f32_16x16x32_bf16(qfrag[c], bfrag, sacc[nt], 0, 0, 0);
      }
    }
    const bool diag = (t0 == s0);
    #pragma unroll
    for (int nt = 0; nt < 4; ++nt) {
      #pragma unroll
      for (int r = 0; r < 4; ++r) {
        float v = sacc[nt][r] * scale;
        if (diag) {
          const int srow = wave * 16 + quad * 4 + r;
          const int tcol = nt * 16 + lid;
          if (tcol > srow) v = -INFINITY;
        }
        sacc[nt][r] = v;
      }
    }
    // Online softmax: row max over 64 cols (4 tiles + 16-lid butterfly).
    float alpha[4], rsum[4];
    #pragma unroll
    for (int r = 0; r < 4; ++r) {
      float v = fmaxf(fmaxf(sacc[0][r], sacc[1][r]), fmaxf(sacc[2][r], sacc[3][r]));
      v = fmaxf(v, __shfl_xor(v, 1));
      v = fmaxf(v, __shfl_xor(v, 2));
      v = fmaxf(v, __shfl_xor(v, 4));
      v = fmaxf(v, __shfl_xor(v, 8));
      const float mnew = fmaxf(m_i[r], v);
      alpha[r] = __expf(m_i[r] - mnew);
      m_i[r] = mnew;
      rsum[r] = 0.f;
    }
    // P = exp(S - m): C-layout -> A-layout via wave-private LDS.
    #pragma unroll
    for (int nt = 0; nt < 4; ++nt) {
      #pragma unroll
      for (int r = 0; r < 4; ++r) {
        const float p = __expf(sacc[nt][r] - m_i[r]);
        rsum[r] += p;
        Ps[wave][quad * 4 + r][nt * 16 + lid] = (bf16_t)p;
      }
    }
    #pragma unroll
    for (int r = 0; r < 4; ++r) {
      float v = rsum[r];
      v += __shfl_xor(v, 1);
      v += __shfl_xor(v, 2);
      v += __shfl_xor(v, 4);
      v += __shfl_xor(v, 8);
      l_i[r] = l_i[r] * alpha[r] + v;
    }
    #pragma unroll
    for (int dt = 0; dt < 4; ++dt) {
      #pragma unroll
      for (int r = 0; r < 4; ++r) oacc[dt][r] *= alpha[r];
    }
    __syncthreads();  // ensure P writes visible before fragment reads
    // O += P * V  (A = P from LDS, Bt = V^T tile)
    #pragma unroll
    for (int c = 0; c < 2; ++c) {
      bf16x8 pfrag = *(const bf16x8*)&Ps[wave][lid][c * 32 + quad * 8];
      #pragma unroll
      for (int dt = 0; dt < 4; ++dt) {
        bf16x8 vfrag = *(const bf16x8*)&Vs[dt * 16 + lid][c * 32 + quad * 8];
        oacc[dt] = __builtin_amdgcn_mfma_f32_16x16x32_bf16(pfrag, vfrag, oacc[dt], 0, 0, 0);
      }
    }
  }

  #pragma unroll
  for (int dt = 0; dt < 4; ++dt) {
    #pragma unroll
    for (int r = 0; r < 4; ++r) {
      const int row = s0 + wave * 16 + quad * 4 + r;
      const int d = dt * 16 + lid;
      O[(size_t)row * C_DIM + h * HS_DIM + d] = (bf16_t)(oacc[dt][r] / l_i[r]);
    }
  }
}

// ---------------------------------------------------------------------------
// Out projection for ONE batch: out = O @ Wp^T + bp, FP32 STORES.
// A = O (bf16), Bt = Wp fp32 staged -> bf16 (Wp[j][c] is the NT operand).
// ---------------------------------------------------------------------------
__global__ __launch_bounds__(256) void gemm_out_kernel(
    const bf16_t* __restrict__ A,     // [2048,1024] O
    const float* __restrict__ Wp,     // [1024,1024]
    const float* __restrict__ bias,   // [1024]
    float* __restrict__ out) {        // [2048,1024] fp32 (one batch)
  __shared__ __align__(16) bf16_t As[64][72];
  __shared__ __align__(16) bf16_t Bs[64][72];
  const int m0 = blockIdx.x * 64;
  const int n0 = blockIdx.y * 64;
  const int tid = threadIdx.x;
  const int wave = tid >> 6, lane = tid & 63, quad = lane >> 4, lid = lane & 15;
  const int sr = tid >> 3, sc = (tid & 7) << 3;

  f32x4 acc[4] = {};

  for (int k0 = 0; k0 < C_DIM; k0 += 64) {
    *(uint4*)&As[sr][sc]      = *(const uint4*)(A + (size_t)(m0 + sr) * C_DIM + k0 + sc);
    *(uint4*)&As[sr + 32][sc] = *(const uint4*)(A + (size_t)(m0 + sr + 32) * C_DIM + k0 + sc);
    cvt8(&Bs[sr][sc],      Wp + (size_t)(n0 + sr) * C_DIM + k0 + sc);
    cvt8(&Bs[sr + 32][sc], Wp + (size_t)(n0 + sr + 32) * C_DIM + k0 + sc);
    __syncthreads();
    #pragma unroll
    for (int c = 0; c < 2; ++c) {
      bf16x8 afrag = *(const bf16x8*)&As[wave * 16 + lid][c * 32 + quad * 8];
      #pragma unroll
      for (int nt = 0; nt < 4; ++nt) {
        bf16x8 bfrag = *(const bf16x8*)&Bs[nt * 16 + lid][c * 32 + quad * 8];
        acc[nt] = __builtin_amdgcn_mfma_f32_16x16x32_bf16(afrag, bfrag, acc[nt], 0, 0, 0);
      }
    }
    __syncthreads();
  }

  #pragma unroll
  for (int nt = 0; nt < 4; ++nt) {
    #pragma unroll
    for (int r = 0; r < 4; ++r) {
      const int row = m0 + wave * 16 + quad * 4 + r;
      const int col = n0 + nt * 16 + lid;
      out[(size_t)row * C_DIM + col] = acc[nt][r] + bias[col];
    }
  }
}

// ---------------------------------------------------------------------------
extern "C" void kernel_launch(void* const* d_in, const int* in_sizes, int n_in,
                              void* d_out, int out_size, void* d_ws, size_t ws_size,
                              hipStream_t stream) {
  // Dict order [x,Wq,Wk,Wv,Wp,bp] (confirmed r4); keep sorted-order hedge.
  const float *x, *Wq, *Wk, *Wv, *Wp, *bp;
  if (in_sizes[0] == 4 * S_LEN * C_DIM) {        // dict order
    x  = (const float*)d_in[0];
    Wq = (const float*)d_in[1];
    Wk = (const float*)d_in[2];
    Wv = (const float*)d_in[3];
    Wp = (const float*)d_in[4];
    bp = (const float*)d_in[5];
  } else {                                        // key-sorted [Wk,Wp,Wq,Wv,bp,x]
    Wk = (const float*)d_in[0];
    Wp = (const float*)d_in[1];
    Wq = (const float*)d_in[2];
    Wv = (const float*)d_in[3];
    bp = (const float*)d_in[4];
    x  = (const float*)d_in[5];
  }
  float* out = (float*)d_out;   // reference output dtype is float32

  // Per-batch workspace: 4 x [2048,1024] bf16 = 16 MB total.
  const size_t NB = (size_t)S_LEN * C_DIM;  // 2 M elements
  bf16_t* ws  = (bf16_t*)d_ws;
  bf16_t* Qb  = ws;            // [2048,1024]
  bf16_t* Kb  = Qb + NB;       // [2048,1024]
  bf16_t* VTb = Kb + NB;       // [16,64,2048]
  bf16_t* Ob  = VTb + NB;      // [2048,1024]

  for (int b = 0; b < 4; ++b) {
    const float* xb = x + (size_t)b * NB;
    float* outb = out + (size_t)b * NB;
    gemm_qkv_kernel<<<dim3(32, 48), 256, 0, stream>>>(xb, Wq, Wk, Wv, Qb, Kb, VTb);
    flash_attn_kernel<<<dim3(32, 16), 256, 0, stream>>>(Qb, Kb, VTb, Ob);
    gemm_out_kernel<<<dim3(32, 16), 256, 0, stream>>>(Ob, Wp, bp, outb);
  }
}

// Round 7
// 526.674 us; speedup vs baseline: 1.3136x; 1.3136x over previous
//
#include <hip/hip_runtime.h>
#include <hip/hip_bf16.h>
#include <math.h>

// B=4, S=2048, C=1024, H=16, HS=64
// Inputs (fp32, dict order): x[4,2048,1024], Wq/Wk/Wv[16,1024,64],
//                            Wp[1024,1024], bp[1024]
// Output: FP32 [4,2048,1024]
// R7: batch-fused 3-launch pipeline; 128x128 GEMM tiles (m93 ladder);
// LPT-ordered flash (descending s0). ws = 64 MB.

typedef __bf16 bf16_t;
typedef __bf16 bf16x8 __attribute__((ext_vector_type(8)));
typedef float f32x4 __attribute__((ext_vector_type(4)));

#define S_LEN 2048
#define C_DIM 1024
#define NHEAD 16
#define HS_DIM 64
#define MROWS 8192   // B*S

__device__ __forceinline__ void cvt8(bf16_t* dst, const float* __restrict__ src) {
  const float4 a = *(const float4*)src;
  const float4 b = *(const float4*)(src + 4);
  bf16x8 v;
  v[0] = (bf16_t)a.x; v[1] = (bf16_t)a.y; v[2] = (bf16_t)a.z; v[3] = (bf16_t)a.w;
  v[4] = (bf16_t)b.x; v[5] = (bf16_t)b.y; v[6] = (bf16_t)b.z; v[7] = (bf16_t)b.w;
  *(bf16x8*)dst = v;
}

// ---------------------------------------------------------------------------
// QKV projection, all batches: x[8192,1024] x {Wq,Wk,Wv}[16,1024,64].
// 128x128x64 tiles, 4 waves in 2x2 (ww,wc), 4x4 16x16 accs per wave.
// B-operand staged transposed: Bs[(h-h0)*64+d][c]. Scatter epilogue:
// Q[row,h*64+d], K[row,h*64+d], VT[(b*16+h)*64+d, s].
// ---------------------------------------------------------------------------
__global__ __launch_bounds__(256) void gemm_qkv128(
    const float* __restrict__ x,
    const float* __restrict__ Wq, const float* __restrict__ Wk,
    const float* __restrict__ Wv,
    bf16_t* __restrict__ Q, bf16_t* __restrict__ K, bf16_t* __restrict__ VT) {
  __shared__ __align__(16) bf16_t As[128][72];
  __shared__ __align__(16) bf16_t Bs[128][72];
  const int m0 = blockIdx.x * 128;
  const int n0 = blockIdx.y * 128;          // n = wsel*1024 + h*64 + d
  const int wsel = n0 >> 10;
  const int h0 = (n0 >> 6) & 15;            // tile spans heads h0, h0+1
  const float* Wbase = (wsel == 0 ? Wq : (wsel == 1 ? Wk : Wv));

  const int tid = threadIdx.x;
  const int wave = tid >> 6, lane = tid & 63, quad = lane >> 4, lid = lane & 15;
  const int ww = wave >> 1, wc = wave & 1;
  const int ar = tid >> 1, ac = (tid & 1) << 5;     // A: row 0..127, col 0/32
  const int btc = tid >> 2, btd = (tid & 3) << 4;   // B^T: c 0..63, d0 0..48

  f32x4 acc[4][4] = {};

  for (int k0 = 0; k0 < C_DIM; k0 += 64) {
    #pragma unroll
    for (int j = 0; j < 32; j += 8)
      cvt8(&As[ar][ac + j], x + (size_t)(m0 + ar) * C_DIM + k0 + ac + j);
    #pragma unroll
    for (int hh = 0; hh < 2; ++hh) {
      const float* Wrow = Wbase + ((size_t)(h0 + hh) * C_DIM + k0 + btc) * HS_DIM + btd;
      #pragma unroll
      for (int j = 0; j < 16; j += 4) {
        const float4 w4 = *(const float4*)(Wrow + j);
        Bs[hh * 64 + btd + j + 0][btc] = (bf16_t)w4.x;
        Bs[hh * 64 + btd + j + 1][btc] = (bf16_t)w4.y;
        Bs[hh * 64 + btd + j + 2][btc] = (bf16_t)w4.z;
        Bs[hh * 64 + btd + j + 3][btc] = (bf16_t)w4.w;
      }
    }
    __syncthreads();
    #pragma unroll
    for (int c = 0; c < 2; ++c) {
      bf16x8 af[4], bf[4];
      #pragma unroll
      for (int mt = 0; mt < 4; ++mt)
        af[mt] = *(const bf16x8*)&As[ww * 64 + mt * 16 + lid][c * 32 + quad * 8];
      #pragma unroll
      for (int nt = 0; nt < 4; ++nt)
        bf[nt] = *(const bf16x8*)&Bs[wc * 64 + nt * 16 + lid][c * 32 + quad * 8];
      #pragma unroll
      for (int mt = 0; mt < 4; ++mt)
        #pragma unroll
        for (int nt = 0; nt < 4; ++nt)
          acc[mt][nt] = __builtin_amdgcn_mfma_f32_16x16x32_bf16(af[mt], bf[nt], acc[mt][nt], 0, 0, 0);
    }
    __syncthreads();
  }

  #pragma unroll
  for (int mt = 0; mt < 4; ++mt) {
    #pragma unroll
    for (int nt = 0; nt < 4; ++nt) {
      #pragma unroll
      for (int r = 0; r < 4; ++r) {
        const int row = m0 + ww * 64 + mt * 16 + quad * 4 + r;   // b*2048+s
        const int col = n0 + wc * 64 + nt * 16 + lid;
        const int h = (col >> 6) & 15, d = col & 63;
        const bf16_t bv = (bf16_t)acc[mt][nt][r];
        if (wsel == 0) {
          Q[(size_t)row * C_DIM + h * HS_DIM + d] = bv;
        } else if (wsel == 1) {
          K[(size_t)row * C_DIM + h * HS_DIM + d] = bv;
        } else {
          const int b = row >> 11, s = row & 2047;
          VT[((size_t)(b * NHEAD + h) * HS_DIM + d) * S_LEN + s] = bv;
        }
      }
    }
  }
}

// ---------------------------------------------------------------------------
// Flash attention (causal), all batches. grid = (32 tiles desc, 64 bh).
// Block = 4 waves, one (bh, 64-row Q tile); LPT order: s0 = (31-bx)*64.
// ---------------------------------------------------------------------------
__global__ __launch_bounds__(256) void flash_attn_kernel(
    const bf16_t* __restrict__ Q,   // [8192,1024]
    const bf16_t* __restrict__ Kb,  // [8192,1024]
    const bf16_t* __restrict__ VT,  // [64,64,2048]
    bf16_t* __restrict__ O) {       // [8192,1024]
  __shared__ __align__(16) bf16_t Ks[64][72];
  __shared__ __align__(16) bf16_t Vs[64][72];
  __shared__ __align__(16) bf16_t Ps[4][16][72];
  const int s0 = (31 - blockIdx.x) * 64;     // descending: long blocks first
  const int bh = blockIdx.y;                 // b*16 + h
  const int b = bh >> 4, h = bh & 15;
  const int rb = b * S_LEN;                  // row base in [8192,*]
  const int tid = threadIdx.x;
  const int wave = tid >> 6, lane = tid & 63, quad = lane >> 4, lid = lane & 15;

  const size_t qbase = (size_t)(rb + s0 + wave * 16 + lid) * C_DIM + h * HS_DIM;
  bf16x8 qfrag[2];
  qfrag[0] = *(const bf16x8*)(Q + qbase + quad * 8);
  qfrag[1] = *(const bf16x8*)(Q + qbase + 32 + quad * 8);

  f32x4 oacc[4] = {};
  float m_i[4], l_i[4];
  #pragma unroll
  for (int r = 0; r < 4; ++r) { m_i[r] = -INFINITY; l_i[r] = 0.f; }

  const int sr = tid >> 3, sc = (tid & 7) << 3;
  const float scale = 0.125f;

  for (int t0 = 0; t0 <= s0; t0 += 64) {
    __syncthreads();
    *(uint4*)&Ks[sr][sc]      = *(const uint4*)(Kb + (size_t)(rb + t0 + sr) * C_DIM + h * HS_DIM + sc);
    *(uint4*)&Ks[sr + 32][sc] = *(const uint4*)(Kb + (size_t)(rb + t0 + sr + 32) * C_DIM + h * HS_DIM + sc);
    *(uint4*)&Vs[sr][sc]      = *(const uint4*)(VT + ((size_t)bh * HS_DIM + sr) * S_LEN + t0 + sc);
    *(uint4*)&Vs[sr + 32][sc] = *(const uint4*)(VT + ((size_t)bh * HS_DIM + sr + 32) * S_LEN + t0 + sc);
    __syncthreads();

    f32x4 sacc[4] = {};
    #pragma unroll
    for (int c = 0; c < 2; ++c) {
      #pragma unroll
      for (int nt = 0; nt < 4; ++nt) {
        bf16x8 bfrag = *(const bf16x8*)&Ks[nt * 16 + lid][c * 32 + quad * 8];
        sacc[nt] = __builtin_amdgcn_mfma_f32_16x16x32_bf16(qfrag[c], bfrag, sacc[nt], 0, 0, 0);
      }
    }
    const bool diag = (t0 == s0);
    #pragma unroll
    for (int nt = 0; nt < 4; ++nt) {
      #pragma unroll
      for (int r = 0; r < 4; ++r) {
        float v = sacc[nt][r] * scale;
        if (diag) {
          const int srow = wave * 16 + quad * 4 + r;
          const int tcol = nt * 16 + lid;
          if (tcol > srow) v = -INFINITY;
        }
        sacc[nt][r] = v;
      }
    }
    float alpha[4], rsum[4];
    #pragma unroll
    for (int r = 0; r < 4; ++r) {
      float v = fmaxf(fmaxf(sacc[0][r], sacc[1][r]), fmaxf(sacc[2][r], sacc[3][r]));
      v = fmaxf(v, __shfl_xor(v, 1));
      v = fmaxf(v, __shfl_xor(v, 2));
      v = fmaxf(v, __shfl_xor(v, 4));
      v = fmaxf(v, __shfl_xor(v, 8));
      const float mnew = fmaxf(m_i[r], v);
      alpha[r] = __expf(m_i[r] - mnew);
      m_i[r] = mnew;
      rsum[r] = 0.f;
    }
    #pragma unroll
    for (int nt = 0; nt < 4; ++nt) {
      #pragma unroll
      for (int r = 0; r < 4; ++r) {
        const float p = __expf(sacc[nt][r] - m_i[r]);
        rsum[r] += p;
        Ps[wave][quad * 4 + r][nt * 16 + lid] = (bf16_t)p;
      }
    }
    #pragma unroll
    for (int r = 0; r < 4; ++r) {
      float v = rsum[r];
      v += __shfl_xor(v, 1);
      v += __shfl_xor(v, 2);
      v += __shfl_xor(v, 4);
      v += __shfl_xor(v, 8);
      l_i[r] = l_i[r] * alpha[r] + v;
    }
    #pragma unroll
    for (int dt = 0; dt < 4; ++dt) {
      #pragma unroll
      for (int r = 0; r < 4; ++r) oacc[dt][r] *= alpha[r];
    }
    __syncthreads();
    #pragma unroll
    for (int c = 0; c < 2; ++c) {
      bf16x8 pfrag = *(const bf16x8*)&Ps[wave][lid][c * 32 + quad * 8];
      #pragma unroll
      for (int dt = 0; dt < 4; ++dt) {
        bf16x8 vfrag = *(const bf16x8*)&Vs[dt * 16 + lid][c * 32 + quad * 8];
        oacc[dt] = __builtin_amdgcn_mfma_f32_16x16x32_bf16(pfrag, vfrag, oacc[dt], 0, 0, 0);
      }
    }
  }

  #pragma unroll
  for (int dt = 0; dt < 4; ++dt) {
    #pragma unroll
    for (int r = 0; r < 4; ++r) {
      const int row = rb + s0 + wave * 16 + quad * 4 + r;
      const int d = dt * 16 + lid;
      O[(size_t)row * C_DIM + h * HS_DIM + d] = (bf16_t)(oacc[dt][r] / l_i[r]);
    }
  }
}

// ---------------------------------------------------------------------------
// Output projection, all batches: out = O @ Wp^T + bp, fp32 stores.
// 128x128x64 tiles, same wave structure as gemm_qkv128.
// ---------------------------------------------------------------------------
__global__ __launch_bounds__(256) void gemm_out128(
    const bf16_t* __restrict__ A,    // [8192,1024] O
    const float* __restrict__ Wp,    // [1024,1024]
    const float* __restrict__ bias,  // [1024]
    float* __restrict__ out) {       // [8192,1024] fp32
  __shared__ __align__(16) bf16_t As[128][72];
  __shared__ __align__(16) bf16_t Bs[128][72];
  const int m0 = blockIdx.x * 128;
  const int n0 = blockIdx.y * 128;
  const int tid = threadIdx.x;
  const int wave = tid >> 6, lane = tid & 63, quad = lane >> 4, lid = lane & 15;
  const int ww = wave >> 1, wc = wave & 1;
  const int ar = tid >> 1, ac = (tid & 1) << 5;

  f32x4 acc[4][4] = {};

  for (int k0 = 0; k0 < C_DIM; k0 += 64) {
    #pragma unroll
    for (int j = 0; j < 32; j += 16) {
      *(uint4*)&As[ar][ac + j]     = *(const uint4*)(A + (size_t)(m0 + ar) * C_DIM + k0 + ac + j);
      *(uint4*)&As[ar][ac + j + 8] = *(const uint4*)(A + (size_t)(m0 + ar) * C_DIM + k0 + ac + j + 8);
    }
    #pragma unroll
    for (int j = 0; j < 32; j += 8)
      cvt8(&Bs[ar][ac + j], Wp + (size_t)(n0 + ar) * C_DIM + k0 + ac + j);
    __syncthreads();
    #pragma unroll
    for (int c = 0; c < 2; ++c) {
      bf16x8 af[4], bf[4];
      #pragma unroll
      for (int mt = 0; mt < 4; ++mt)
        af[mt] = *(const bf16x8*)&As[ww * 64 + mt * 16 + lid][c * 32 + quad * 8];
      #pragma unroll
      for (int nt = 0; nt < 4; ++nt)
        bf[nt] = *(const bf16x8*)&Bs[wc * 64 + nt * 16 + lid][c * 32 + quad * 8];
      #pragma unroll
      for (int mt = 0; mt < 4; ++mt)
        #pragma unroll
        for (int nt = 0; nt < 4; ++nt)
          acc[mt][nt] = __builtin_amdgcn_mfma_f32_16x16x32_bf16(af[mt], bf[nt], acc[mt][nt], 0, 0, 0);
    }
    __syncthreads();
  }

  #pragma unroll
  for (int mt = 0; mt < 4; ++mt) {
    #pragma unroll
    for (int nt = 0; nt < 4; ++nt) {
      #pragma unroll
      for (int r = 0; r < 4; ++r) {
        const int row = m0 + ww * 64 + mt * 16 + quad * 4 + r;
        const int col = n0 + wc * 64 + nt * 16 + lid;
        out[(size_t)row * C_DIM + col] = acc[mt][nt][r] + bias[col];
      }
    }
  }
}

// ---------------------------------------------------------------------------
extern "C" void kernel_launch(void* const* d_in, const int* in_sizes, int n_in,
                              void* d_out, int out_size, void* d_ws, size_t ws_size,
                              hipStream_t stream) {
  const float *x, *Wq, *Wk, *Wv, *Wp, *bp;
  if (in_sizes[0] == MROWS * C_DIM) {            // dict order (confirmed r4/r6)
    x  = (const float*)d_in[0];
    Wq = (const float*)d_in[1];
    Wk = (const float*)d_in[2];
    Wv = (const float*)d_in[3];
    Wp = (const float*)d_in[4];
    bp = (const float*)d_in[5];
  } else {                                        // key-sorted hedge
    Wk = (const float*)d_in[0];
    Wp = (const float*)d_in[1];
    Wq = (const float*)d_in[2];
    Wv = (const float*)d_in[3];
    bp = (const float*)d_in[4];
    x  = (const float*)d_in[5];
  }
  float* out = (float*)d_out;

  // ws: 4 bf16 buffers of [8192,1024] = 64 MB total.
  const size_t NB = (size_t)MROWS * C_DIM;   // 8 M elements
  bf16_t* ws  = (bf16_t*)d_ws;
  bf16_t* Qb  = ws;            // [8192,1024]
  bf16_t* Kb  = Qb + NB;       // [8192,1024]
  bf16_t* VTb = Kb + NB;       // [64,64,2048]
  bf16_t* Ob  = VTb + NB;      // [8192,1024]

  gemm_qkv128<<<dim3(64, 24), 256, 0, stream>>>(x, Wq, Wk, Wv, Qb, Kb, VTb);
  flash_attn_kernel<<<dim3(32, 64), 256, 0, stream>>>(Qb, Kb, VTb, Ob);
  gemm_out128<<<dim3(64, 8), 256, 0, stream>>>(Ob, Wp, bp, out);
}

// Round 8
// 494.900 us; speedup vs baseline: 1.3979x; 1.0642x over previous
//
#include <hip/hip_runtime.h>
#include <hip/hip_bf16.h>
#include <math.h>

// B=4, S=2048, C=1024, H=16, HS=64
// Inputs (fp32, dict order): x[4,2048,1024], Wq/Wk/Wv[16,1024,64],
//                            Wp[1024,1024], bp[1024]
// Output: FP32 [4,2048,1024]
// R8: flash = 1-barrier double-buffered pipeline (register prefetch of K/V);
// QKV GEMM reads pre-packed bf16 WT (pack kernel); ws = 64 MB (WT aliases Ob).

typedef __bf16 bf16_t;
typedef __bf16 bf16x8 __attribute__((ext_vector_type(8)));
typedef float f32x4 __attribute__((ext_vector_type(4)));

#define S_LEN 2048
#define C_DIM 1024
#define NHEAD 16
#define HS_DIM 64
#define MROWS 8192   // B*S

__device__ __forceinline__ void cvt8(bf16_t* dst, const float* __restrict__ src) {
  const float4 a = *(const float4*)src;
  const float4 b = *(const float4*)(src + 4);
  bf16x8 v;
  v[0] = (bf16_t)a.x; v[1] = (bf16_t)a.y; v[2] = (bf16_t)a.z; v[3] = (bf16_t)a.w;
  v[4] = (bf16_t)b.x; v[5] = (bf16_t)b.y; v[6] = (bf16_t)b.z; v[7] = (bf16_t)b.w;
  *(bf16x8*)dst = v;
}

// ---------------------------------------------------------------------------
// Pack Wq,Wk,Wv (fp32 [16,1024,64]) -> bf16 WT[3072,1024]:
// WT[wsel*1024+h*64+d][c] = W[h][c][d].  (verified: r2 == r5 bit-identical)
// ---------------------------------------------------------------------------
__global__ __launch_bounds__(256) void pack_w_kernel(
    const float* __restrict__ Wq, const float* __restrict__ Wk,
    const float* __restrict__ Wv, bf16_t* __restrict__ WT) {
  __shared__ __align__(16) float tile[64][68];
  const int wsel = blockIdx.z;
  const int h = blockIdx.y;
  const int c0 = blockIdx.x * 64;
  const float* W = (wsel == 0 ? Wq : (wsel == 1 ? Wk : Wv)) + (size_t)h * (C_DIM * HS_DIM);
  const int tr = threadIdx.x >> 2;          // 0..63 (c-row within tile)
  const int tc = (threadIdx.x & 3) << 4;    // 0,16,32,48
  #pragma unroll
  for (int j = 0; j < 16; j += 4)
    *(float4*)&tile[tr][tc + j] = *(const float4*)(W + (size_t)(c0 + tr) * HS_DIM + tc + j);
  __syncthreads();
  const int d = threadIdx.x >> 2;           // 0..63
  const int cb = (threadIdx.x & 3) << 4;    // 0,16,32,48
  bf16_t* dst = WT + ((size_t)(wsel * 1024 + h * 64 + d)) * C_DIM + c0 + cb;
  #pragma unroll
  for (int i = 0; i < 16; ++i) dst[i] = (bf16_t)tile[cb + i][d];
}

// ---------------------------------------------------------------------------
// QKV projection: x[8192,1024](fp32) x WT[3072,1024](bf16)^T.
// 128x128x64 tiles, 4 waves in 2x2, 4x4 accs/wave. Scatter epilogue.
// ---------------------------------------------------------------------------
__global__ __launch_bounds__(256) void gemm_qkv128(
    const float* __restrict__ x, const bf16_t* __restrict__ WT,
    bf16_t* __restrict__ Q, bf16_t* __restrict__ K, bf16_t* __restrict__ VT) {
  __shared__ __align__(16) bf16_t As[128][72];
  __shared__ __align__(16) bf16_t Bs[128][72];
  const int m0 = blockIdx.x * 128;
  const int n0 = blockIdx.y * 128;
  const int tid = threadIdx.x;
  const int wave = tid >> 6, lane = tid & 63, quad = lane >> 4, lid = lane & 15;
  const int ww = wave >> 1, wc = wave & 1;
  const int ar = tid >> 1, ac = (tid & 1) << 5;

  f32x4 acc[4][4] = {};

  for (int k0 = 0; k0 < C_DIM; k0 += 64) {
    #pragma unroll
    for (int j = 0; j < 32; j += 8)
      cvt8(&As[ar][ac + j], x + (size_t)(m0 + ar) * C_DIM + k0 + ac + j);
    #pragma unroll
    for (int j = 0; j < 32; j += 8)
      *(uint4*)&Bs[ar][ac + j] = *(const uint4*)(WT + (size_t)(n0 + ar) * C_DIM + k0 + ac + j);
    __syncthreads();
    #pragma unroll
    for (int c = 0; c < 2; ++c) {
      bf16x8 af[4], bfr[4];
      #pragma unroll
      for (int mt = 0; mt < 4; ++mt)
        af[mt] = *(const bf16x8*)&As[ww * 64 + mt * 16 + lid][c * 32 + quad * 8];
      #pragma unroll
      for (int nt = 0; nt < 4; ++nt)
        bfr[nt] = *(const bf16x8*)&Bs[wc * 64 + nt * 16 + lid][c * 32 + quad * 8];
      #pragma unroll
      for (int mt = 0; mt < 4; ++mt)
        #pragma unroll
        for (int nt = 0; nt < 4; ++nt)
          acc[mt][nt] = __builtin_amdgcn_mfma_f32_16x16x32_bf16(af[mt], bfr[nt], acc[mt][nt], 0, 0, 0);
    }
    __syncthreads();
  }

  #pragma unroll
  for (int mt = 0; mt < 4; ++mt) {
    #pragma unroll
    for (int nt = 0; nt < 4; ++nt) {
      #pragma unroll
      for (int r = 0; r < 4; ++r) {
        const int row = m0 + ww * 64 + mt * 16 + quad * 4 + r;
        const int col = n0 + wc * 64 + nt * 16 + lid;
        const int wsel = col >> 10, h = (col >> 6) & 15, d = col & 63;
        const bf16_t bv = (bf16_t)acc[mt][nt][r];
        if (wsel == 0) {
          Q[(size_t)row * C_DIM + h * HS_DIM + d] = bv;
        } else if (wsel == 1) {
          K[(size_t)row * C_DIM + h * HS_DIM + d] = bv;
        } else {
          const int b = row >> 11, s = row & 2047;
          VT[((size_t)(b * NHEAD + h) * HS_DIM + d) * S_LEN + s] = bv;
        }
      }
    }
  }
}

// ---------------------------------------------------------------------------
// Flash attention (causal), 1-barrier double-buffered pipeline.
// grid (32 desc-LPT, 64 bh); block = 4 waves, one (bh, 64-row Q tile).
// Per iter: prefetch K/V tile i+1 to regs -> compute on LDS[i&1] ->
// write regs to LDS[1-(i&1)] -> ONE barrier.
// ---------------------------------------------------------------------------
__global__ __launch_bounds__(256) void flash_attn_kernel(
    const bf16_t* __restrict__ Q,   // [8192,1024]
    const bf16_t* __restrict__ Kb,  // [8192,1024]
    const bf16_t* __restrict__ VT,  // [64,64,2048]
    bf16_t* __restrict__ O) {       // [8192,1024]
  __shared__ __align__(16) bf16_t Ks[2][64][72];
  __shared__ __align__(16) bf16_t Vs[2][64][72];
  __shared__ __align__(16) bf16_t Ps[4][16][72];
  const int s0 = (31 - blockIdx.x) * 64;     // LPT: long blocks first
  const int bh = blockIdx.y;
  const int b = bh >> 4, h = bh & 15;
  const int rb = b * S_LEN;
  const int tid = threadIdx.x;
  const int wave = tid >> 6, lane = tid & 63, quad = lane >> 4, lid = lane & 15;
  const int sr = tid >> 3, sc = (tid & 7) << 3;
  const float scale = 0.125f;

  // Q fragments (A-layout)
  const size_t qbase = (size_t)(rb + s0 + wave * 16 + lid) * C_DIM + h * HS_DIM;
  bf16x8 qfrag[2];
  qfrag[0] = *(const bf16x8*)(Q + qbase + quad * 8);
  qfrag[1] = *(const bf16x8*)(Q + qbase + 32 + quad * 8);

  f32x4 oacc[4] = {};
  float m_i[4], l_i[4];
  #pragma unroll
  for (int r = 0; r < 4; ++r) { m_i[r] = -INFINITY; l_i[r] = 0.f; }

  // per-thread staging addresses for K/V tile at t0
  const bf16_t* kbase = Kb + (size_t)(rb + sr) * C_DIM + h * HS_DIM + sc;  // + t0*C_DIM
  const bf16_t* vbase = VT + ((size_t)bh * HS_DIM + sr) * S_LEN + sc;     // + t0

  const int nIter = (s0 >> 6) + 1;

  // Prolog: load tile 0 -> LDS[0]
  {
    uint4 k0r = *(const uint4*)(kbase);
    uint4 k1r = *(const uint4*)(kbase + 32 * C_DIM);
    uint4 v0r = *(const uint4*)(vbase);
    uint4 v1r = *(const uint4*)(vbase + 32 * S_LEN);
    *(uint4*)&Ks[0][sr][sc]      = k0r;
    *(uint4*)&Ks[0][sr + 32][sc] = k1r;
    *(uint4*)&Vs[0][sr][sc]      = v0r;
    *(uint4*)&Vs[0][sr + 32][sc] = v1r;
  }
  __syncthreads();

  for (int i = 0; i < nIter; ++i) {
    const int p = i & 1;
    const int t0 = i << 6;

    // Prefetch tile i+1 into registers (loads overlap the compute below).
    uint4 k0r, k1r, v0r, v1r;
    const bool haveNext = (i + 1 < nIter);
    if (haveNext) {
      const bf16_t* kp = kbase + (size_t)(t0 + 64) * C_DIM;
      const bf16_t* vp = vbase + (t0 + 64);
      k0r = *(const uint4*)(kp);
      k1r = *(const uint4*)(kp + 32 * C_DIM);
      v0r = *(const uint4*)(vp);
      v1r = *(const uint4*)(vp + 32 * S_LEN);
    }

    // ---- compute on buffer p ----
    f32x4 sacc[4] = {};
    #pragma unroll
    for (int c = 0; c < 2; ++c) {
      #pragma unroll
      for (int nt = 0; nt < 4; ++nt) {
        bf16x8 bfrag = *(const bf16x8*)&Ks[p][nt * 16 + lid][c * 32 + quad * 8];
        sacc[nt] = __builtin_amdgcn_mfma_f32_16x16x32_bf16(qfrag[c], bfrag, sacc[nt], 0, 0, 0);
      }
    }
    const bool diag = (t0 == s0);
    #pragma unroll
    for (int nt = 0; nt < 4; ++nt) {
      #pragma unroll
      for (int r = 0; r < 4; ++r) {
        float v = sacc[nt][r] * scale;
        if (diag) {
          const int srow = wave * 16 + quad * 4 + r;
          const int tcol = nt * 16 + lid;
          if (tcol > srow) v = -INFINITY;
        }
        sacc[nt][r] = v;
      }
    }
    float alpha[4], rsum[4];
    #pragma unroll
    for (int r = 0; r < 4; ++r) {
      float v = fmaxf(fmaxf(sacc[0][r], sacc[1][r]), fmaxf(sacc[2][r], sacc[3][r]));
      v = fmaxf(v, __shfl_xor(v, 1));
      v = fmaxf(v, __shfl_xor(v, 2));
      v = fmaxf(v, __shfl_xor(v, 4));
      v = fmaxf(v, __shfl_xor(v, 8));
      const float mnew = fmaxf(m_i[r], v);
      alpha[r] = __expf(m_i[r] - mnew);
      m_i[r] = mnew;
      rsum[r] = 0.f;
    }
    #pragma unroll
    for (int nt = 0; nt < 4; ++nt) {
      #pragma unroll
      for (int r = 0; r < 4; ++r) {
        const float pv = __expf(sacc[nt][r] - m_i[r]);
        rsum[r] += pv;
        Ps[wave][quad * 4 + r][nt * 16 + lid] = (bf16_t)pv;   // wave-private
      }
    }
    #pragma unroll
    for (int r = 0; r < 4; ++r) {
      float v = rsum[r];
      v += __shfl_xor(v, 1);
      v += __shfl_xor(v, 2);
      v += __shfl_xor(v, 4);
      v += __shfl_xor(v, 8);
      l_i[r] = l_i[r] * alpha[r] + v;
    }
    #pragma unroll
    for (int dt = 0; dt < 4; ++dt) {
      #pragma unroll
      for (int r = 0; r < 4; ++r) oacc[dt][r] *= alpha[r];
    }
    // P round-trip is same-wave LDS (in-order); PV on buffer p.
    #pragma unroll
    for (int c = 0; c < 2; ++c) {
      bf16x8 pfrag = *(const bf16x8*)&Ps[wave][lid][c * 32 + quad * 8];
      #pragma unroll
      for (int dt = 0; dt < 4; ++dt) {
        bf16x8 vfrag = *(const bf16x8*)&Vs[p][dt * 16 + lid][c * 32 + quad * 8];
        oacc[dt] = __builtin_amdgcn_mfma_f32_16x16x32_bf16(pfrag, vfrag, oacc[dt], 0, 0, 0);
      }
    }
    // ---- write prefetched tile into the idle buffer (no conflict) ----
    if (haveNext) {
      *(uint4*)&Ks[1 - p][sr][sc]      = k0r;
      *(uint4*)&Ks[1 - p][sr + 32][sc] = k1r;
      *(uint4*)&Vs[1 - p][sr][sc]      = v0r;
      *(uint4*)&Vs[1 - p][sr + 32][sc] = v1r;
      __syncthreads();   // single barrier per iteration
    }
  }

  #pragma unroll
  for (int dt = 0; dt < 4; ++dt) {
    #pragma unroll
    for (int r = 0; r < 4; ++r) {
      const int row = rb + s0 + wave * 16 + quad * 4 + r;
      const int d = dt * 16 + lid;
      O[(size_t)row * C_DIM + h * HS_DIM + d] = (bf16_t)(oacc[dt][r] / l_i[r]);
    }
  }
}

// ---------------------------------------------------------------------------
// Output projection: out = O @ Wp^T + bp (fp32 stores). 128x128x64 tiles.
// ---------------------------------------------------------------------------
__global__ __launch_bounds__(256) void gemm_out128(
    const bf16_t* __restrict__ A,    // [8192,1024] O
    const float* __restrict__ Wp,    // [1024,1024]
    const float* __restrict__ bias,  // [1024]
    float* __restrict__ out) {       // [8192,1024] fp32
  __shared__ __align__(16) bf16_t As[128][72];
  __shared__ __align__(16) bf16_t Bs[128][72];
  const int m0 = blockIdx.x * 128;
  const int n0 = blockIdx.y * 128;
  const int tid = threadIdx.x;
  const int wave = tid >> 6, lane = tid & 63, quad = lane >> 4, lid = lane & 15;
  const int ww = wave >> 1, wc = wave & 1;
  const int ar = tid >> 1, ac = (tid & 1) << 5;

  f32x4 acc[4][4] = {};

  for (int k0 = 0; k0 < C_DIM; k0 += 64) {
    #pragma unroll
    for (int j = 0; j < 32; j += 8)
      *(uint4*)&As[ar][ac + j] = *(const uint4*)(A + (size_t)(m0 + ar) * C_DIM + k0 + ac + j);
    #pragma unroll
    for (int j = 0; j < 32; j += 8)
      cvt8(&Bs[ar][ac + j], Wp + (size_t)(n0 + ar) * C_DIM + k0 + ac + j);
    __syncthreads();
    #pragma unroll
    for (int c = 0; c < 2; ++c) {
      bf16x8 af[4], bfr[4];
      #pragma unroll
      for (int mt = 0; mt < 4; ++mt)
        af[mt] = *(const bf16x8*)&As[ww * 64 + mt * 16 + lid][c * 32 + quad * 8];
      #pragma unroll
      for (int nt = 0; nt < 4; ++nt)
        bfr[nt] = *(const bf16x8*)&Bs[wc * 64 + nt * 16 + lid][c * 32 + quad * 8];
      #pragma unroll
      for (int mt = 0; mt < 4; ++mt)
        #pragma unroll
        for (int nt = 0; nt < 4; ++nt)
          acc[mt][nt] = __builtin_amdgcn_mfma_f32_16x16x32_bf16(af[mt], bfr[nt], acc[mt][nt], 0, 0, 0);
    }
    __syncthreads();
  }

  #pragma unroll
  for (int mt = 0; mt < 4; ++mt) {
    #pragma unroll
    for (int nt = 0; nt < 4; ++nt) {
      #pragma unroll
      for (int r = 0; r < 4; ++r) {
        const int row = m0 + ww * 64 + mt * 16 + quad * 4 + r;
        const int col = n0 + wc * 64 + nt * 16 + lid;
        out[(size_t)row * C_DIM + col] = acc[mt][nt][r] + bias[col];
      }
    }
  }
}

// ---------------------------------------------------------------------------
extern "C" void kernel_launch(void* const* d_in, const int* in_sizes, int n_in,
                              void* d_out, int out_size, void* d_ws, size_t ws_size,
                              hipStream_t stream) {
  const float *x, *Wq, *Wk, *Wv, *Wp, *bp;
  if (in_sizes[0] == MROWS * C_DIM) {            // dict order (confirmed)
    x  = (const float*)d_in[0];
    Wq = (const float*)d_in[1];
    Wk = (const float*)d_in[2];
    Wv = (const float*)d_in[3];
    Wp = (const float*)d_in[4];
    bp = (const float*)d_in[5];
  } else {                                        // key-sorted hedge
    Wk = (const float*)d_in[0];
    Wp = (const float*)d_in[1];
    Wq = (const float*)d_in[2];
    Wv = (const float*)d_in[3];
    bp = (const float*)d_in[4];
    x  = (const float*)d_in[5];
  }
  float* out = (float*)d_out;

  // ws = 64 MB: [Ob 16MB (WT aliases its first 6MB; dead before flash)]
  //             [Qb 16MB][Kb 16MB][VTb 16MB]
  const size_t NB = (size_t)MROWS * C_DIM;   // 8 M elements
  bf16_t* ws  = (bf16_t*)d_ws;
  bf16_t* Ob  = ws;            // [8192,1024]
  bf16_t* WT  = ws;            // [3072,1024] — aliases Ob, dead after QKV GEMM
  bf16_t* Qb  = ws + NB;       // [8192,1024]
  bf16_t* Kb  = Qb + NB;       // [8192,1024]
  bf16_t* VTb = Kb + NB;       // [64,64,2048]

  pack_w_kernel<<<dim3(16, 16, 3), 256, 0, stream>>>(Wq, Wk, Wv, WT);
  gemm_qkv128<<<dim3(64, 24), 256, 0, stream>>>(x, WT, Qb, Kb, VTb);
  flash_attn_kernel<<<dim3(32, 64), 256, 0, stream>>>(Qb, Kb, VTb, Ob);
  gemm_out128<<<dim3(64, 8), 256, 0, stream>>>(Ob, Wp, bp, out);
}